// Round 1
// baseline (699.105 us; speedup 1.0000x reference)
//
#include <hip/hip_runtime.h>
#include <stdint.h>

#define NN   8192
#define DIN  512
#define DOUT 512
#define ALPHA 0.2f

typedef float          floatx4  __attribute__((ext_vector_type(4)));
typedef short          shortx8  __attribute__((ext_vector_type(8)));
typedef unsigned short ushortx4 __attribute__((ext_vector_type(4)));
typedef int            intx4    __attribute__((ext_vector_type(4)));

__device__ inline unsigned short f2bf(float x) {
    union { float f; unsigned u; } v; v.f = x;
    return (unsigned short)((v.u + 0x7FFFu + ((v.u >> 16) & 1u)) >> 16);
}
__device__ inline unsigned encf(float x) {
    union { float f; unsigned u; } v; v.f = x;
    return (v.u & 0x80000000u) ? ~v.u : (v.u | 0x80000000u);
}
__device__ inline float decf(unsigned e) {
    union { float f; unsigned u; } v;
    v.u = (e & 0x80000000u) ? (e & 0x7FFFFFFFu) : ~e;
    return v.f;
}

// ---------------------------------------------------------------------------
// Kernel T: WT[n][k] = bf16(W[k][n])   (512x512)
// ---------------------------------------------------------------------------
__global__ __launch_bounds__(256) void transpose_w(const float* __restrict__ W,
                                                   unsigned short* __restrict__ WT) {
    __shared__ float tile[32][33];
    const int t = threadIdx.x;
    const int x = t & 31, y = t >> 5;
    const int tr = (blockIdx.x >> 4) * 32, tc = (blockIdx.x & 15) * 32;
#pragma unroll
    for (int i = 0; i < 4; i++) {
        int r = y + i * 8;
        tile[r][x] = W[(size_t)(tr + r) * DOUT + tc + x];
    }
    __syncthreads();
#pragma unroll
    for (int i = 0; i < 4; i++) {
        int r = y + i * 8;
        WT[(size_t)(tc + r) * DIN + tr + x] = f2bf(tile[x][r]);
    }
}

// ---------------------------------------------------------------------------
// Kernel A: Wh = h @ W  (bf16 MFMA, fp32 acc). Writes WhT[col][row] bf16,
// f1 = Wh@a1, f2 = Wh@a2 (fp32), and atomicMax of max(f2) (encoded).
// Block: 32 rows x 512 cols, 4 waves (each 32r x 128c).
// ---------------------------------------------------------------------------
__global__ __launch_bounds__(256) void gemm_wh(
    const float* __restrict__ h, const unsigned short* __restrict__ WT,
    const float* __restrict__ a, unsigned short* __restrict__ WhT,
    float* __restrict__ f1, float* __restrict__ f2, unsigned* __restrict__ Menc)
{
    __shared__ float f1s[4][32], f2s[4][32];
    const int t = threadIdx.x;
    const int w = t >> 6, lane = t & 63, l15 = lane & 15, q = lane >> 4;
    const int r0 = blockIdx.x * 32;
    const int wc0 = w * 128;

    floatx4 acc[2][8];
    const floatx4 z4 = {0.f, 0.f, 0.f, 0.f};
#pragma unroll
    for (int i = 0; i < 2; i++)
#pragma unroll
        for (int j = 0; j < 8; j++) acc[i][j] = z4;

    for (int kk = 0; kk < DIN; kk += 32) {
        shortx8 af[2];
#pragma unroll
        for (int mt = 0; mt < 2; mt++) {
            const float* hp = &h[(size_t)(r0 + mt * 16 + l15) * DIN + kk + q * 8];
            floatx4 h0 = *(const floatx4*)hp;
            floatx4 h1 = *(const floatx4*)(hp + 4);
            shortx8 v;
            v[0] = (short)f2bf(h0[0]); v[1] = (short)f2bf(h0[1]);
            v[2] = (short)f2bf(h0[2]); v[3] = (short)f2bf(h0[3]);
            v[4] = (short)f2bf(h1[0]); v[5] = (short)f2bf(h1[1]);
            v[6] = (short)f2bf(h1[2]); v[7] = (short)f2bf(h1[3]);
            af[mt] = v;
        }
        shortx8 bf[8];
#pragma unroll
        for (int nt = 0; nt < 8; nt++)
            bf[nt] = *(const shortx8*)&WT[(size_t)(wc0 + nt * 16 + l15) * DIN + kk + q * 8];
#pragma unroll
        for (int mt = 0; mt < 2; mt++)
#pragma unroll
            for (int nt = 0; nt < 8; nt++)
                acc[mt][nt] = __builtin_amdgcn_mfma_f32_16x16x32_bf16(
                    af[mt], bf[nt], acc[mt][nt], 0, 0, 0);
    }

    // epilogue: WhT store + f1/f2 partials
    float a1v[8], a2v[8];
#pragma unroll
    for (int nt = 0; nt < 8; nt++) {
        int col = wc0 + nt * 16 + l15;
        a1v[nt] = a[col];
        a2v[nt] = a[DOUT + col];
    }
    float s1a[2][4], s2a[2][4];
#pragma unroll
    for (int mt = 0; mt < 2; mt++) {
#pragma unroll
        for (int nt = 0; nt < 8; nt++) {
            int col = wc0 + nt * 16 + l15;
            int rowb = r0 + mt * 16 + q * 4;
            ushortx4 pk;
#pragma unroll
            for (int reg = 0; reg < 4; reg++) pk[reg] = f2bf(acc[mt][nt][reg]);
            *(ushortx4*)&WhT[(size_t)col * NN + rowb] = pk;
        }
#pragma unroll
        for (int reg = 0; reg < 4; reg++) {
            float s1 = 0.f, s2 = 0.f;
#pragma unroll
            for (int nt = 0; nt < 8; nt++) {
                s1 += acc[mt][nt][reg] * a1v[nt];
                s2 += acc[mt][nt][reg] * a2v[nt];
            }
            s1 += __shfl_xor(s1, 1, 64); s2 += __shfl_xor(s2, 1, 64);
            s1 += __shfl_xor(s1, 2, 64); s2 += __shfl_xor(s2, 2, 64);
            s1 += __shfl_xor(s1, 4, 64); s2 += __shfl_xor(s2, 4, 64);
            s1 += __shfl_xor(s1, 8, 64); s2 += __shfl_xor(s2, 8, 64);
            s1a[mt][reg] = s1; s2a[mt][reg] = s2;
        }
    }
    if (l15 == 0) {
#pragma unroll
        for (int mt = 0; mt < 2; mt++)
#pragma unroll
            for (int reg = 0; reg < 4; reg++) {
                int rl = mt * 16 + q * 4 + reg;
                f1s[w][rl] = s1a[mt][reg];
                f2s[w][rl] = s2a[mt][reg];
            }
    }
    __syncthreads();
    if (t < 32) {
        float v1 = f1s[0][t] + f1s[1][t] + f1s[2][t] + f1s[3][t];
        float v2 = f2s[0][t] + f2s[1][t] + f2s[2][t] + f2s[3][t];
        f1[r0 + t] = v1;
        f2[r0 + t] = v2;
        float mx = v2;
        mx = fmaxf(mx, __shfl_xor(mx, 1, 64));
        mx = fmaxf(mx, __shfl_xor(mx, 2, 64));
        mx = fmaxf(mx, __shfl_xor(mx, 4, 64));
        mx = fmaxf(mx, __shfl_xor(mx, 8, 64));
        mx = fmaxf(mx, __shfl_xor(mx, 16, 64));
        if (t == 0) atomicMax(Menc, encf(mx));
    }
}

// ---------------------------------------------------------------------------
// Kernel 2: flash-style GAT aggregation. Block = 32 rows x 512 cols, K-tiles
// of 32 neighbors. p computed once per block into padded LDS (stride 40 elems,
// conflict-free b64 writes / b128 reads), bf16 MFMA P@Wh, B-frags straight
// from WhT (global, L2-resident). Double-buffered p -> one barrier/iter.
// m_i = lrelu(f1_i + max f2) is a valid per-row upper bound: no online max.
// ---------------------------------------------------------------------------
__global__ __launch_bounds__(256) void gat_agg(
    const int* __restrict__ adj, const unsigned short* __restrict__ WhT,
    const float* __restrict__ f1, const float* __restrict__ f2,
    const unsigned* __restrict__ Menc, float* __restrict__ out)
{
    __shared__ __align__(16) unsigned short pbuf[2][32 * 40];
    __shared__ float linv[32];
    const int t = threadIdx.x;
    const int w = t >> 6, lane = t & 63, l15 = lane & 15, q = lane >> 4;
    const int r0 = blockIdx.x * 32;
    const int pr = t >> 3, pc = t & 7;   // p-tile ownership: row, 4-col chunk
    const int wc0 = w * 128;

    const float M = decf(*Menc);
    const float f1v = f1[r0 + pr];
    const float mi0 = f1v + M;
    const float mi = fmaxf(mi0, ALPHA * mi0);   // upper bound on every masked e

    float lsum = 0.f;
    floatx4 acc[2][8];
    const floatx4 z4 = {0.f, 0.f, 0.f, 0.f};
#pragma unroll
    for (int i = 0; i < 2; i++)
#pragma unroll
        for (int j = 0; j < 8; j++) acc[i][j] = z4;

    const int* adjrow = adj + (size_t)(r0 + pr) * NN + pc * 4;

    int buf = 0;
    for (int k0 = 0; k0 < NN; k0 += 32, buf ^= 1) {
        // B fragments direct global->reg (issue first, latency hidden by p-comp)
        shortx8 bfr[8];
#pragma unroll
        for (int nt = 0; nt < 8; nt++)
            bfr[nt] = *(const shortx8*)&WhT[(size_t)(wc0 + nt * 16 + l15) * NN + k0 + q * 8];

        intx4   av = *(const intx4*)(adjrow + k0);
        floatx4 fv = *(const floatx4*)&f2[k0 + pc * 4];

        ushortx4 pk;
#pragma unroll
        for (int jj = 0; jj < 4; jj++) {
            float e0 = f1v + fv[jj];
            float e = fmaxf(e0, ALPHA * e0);       // leaky relu
            float p = (av[jj] > 0) ? __expf(e - mi) : 0.f;
            lsum += p;
            pk[jj] = f2bf(p);
        }
        *(ushortx4*)&pbuf[buf][pr * 40 + pc * 4] = pk;
        __syncthreads();

        shortx8 af0 = *(const shortx8*)&pbuf[buf][l15 * 40 + q * 8];
        shortx8 af1 = *(const shortx8*)&pbuf[buf][(16 + l15) * 40 + q * 8];
#pragma unroll
        for (int nt = 0; nt < 8; nt++) {
            acc[0][nt] = __builtin_amdgcn_mfma_f32_16x16x32_bf16(af0, bfr[nt], acc[0][nt], 0, 0, 0);
            acc[1][nt] = __builtin_amdgcn_mfma_f32_16x16x32_bf16(af1, bfr[nt], acc[1][nt], 0, 0, 0);
        }
    }

    // row-sum of p across the 8 chunk-owner lanes (consecutive, same wave)
    lsum += __shfl_xor(lsum, 1, 64);
    lsum += __shfl_xor(lsum, 2, 64);
    lsum += __shfl_xor(lsum, 4, 64);
    if (pc == 0) linv[pr] = 1.f / lsum;
    __syncthreads();

    // epilogue: normalize + ELU + store
#pragma unroll
    for (int mt = 0; mt < 2; mt++) {
        int rl = mt * 16 + q * 4;
#pragma unroll
        for (int nt = 0; nt < 8; nt++) {
            int col = wc0 + nt * 16 + l15;
#pragma unroll
            for (int reg = 0; reg < 4; reg++) {
                float v = acc[mt][nt][reg] * linv[rl + reg];
                out[(size_t)(r0 + rl + reg) * DOUT + col] = (v > 0.f) ? v : (__expf(v) - 1.f);
            }
        }
    }
}

// ---------------------------------------------------------------------------
extern "C" void kernel_launch(void* const* d_in, const int* in_sizes, int n_in,
                              void* d_out, int out_size, void* d_ws, size_t ws_size,
                              hipStream_t stream) {
    const float* h   = (const float*)d_in[0];
    const int*   adj = (const int*)d_in[1];
    const float* W   = (const float*)d_in[2];
    const float* a   = (const float*)d_in[3];
    float* out = (float*)d_out;

    char* ws = (char*)d_ws;
    unsigned short* WT   = (unsigned short*)ws;                        // 512 KB
    unsigned short* WhT  = (unsigned short*)(ws + 524288);             // 8 MB
    float*          f1   = (float*)(ws + 524288 + 8388608);            // 32 KB
    float*          f2   = (float*)(ws + 524288 + 8388608 + 32768);    // 32 KB
    unsigned*       Menc = (unsigned*)(ws + 524288 + 8388608 + 65536); // 4 B

    hipMemsetAsync(Menc, 0, 4, stream);
    transpose_w<<<256, 256, 0, stream>>>(W, WT);
    gemm_wh<<<256, 256, 0, stream>>>(h, WT, a, WhT, f1, f2, Menc);
    gat_agg<<<256, 256, 0, stream>>>(adj, WhT, f1, f2, Menc, out);
}